// Round 6
// baseline (292.295 us; speedup 1.0000x reference)
//
#include <hip/hip_runtime.h>
#include <hip/hip_bf16.h>
#include <math.h>

typedef __bf16 bf16x8v __attribute__((ext_vector_type(8)));
typedef __bf16 bf16x4v __attribute__((ext_vector_type(4)));
typedef float  f32x4   __attribute__((ext_vector_type(4)));

#define D_DIM 512
#define P_DIM 128
#define TEMP  0.1f
#define RPB   256
#define THREADS 1024
#define LDA_ROW 68   // bf16 elems per sA row (64 + 4 pad) -> 136 B stride, 2-way banks

// ---- pre-kernel: protos fp32 -> bf16 FRAGMENT ORDER into workspace ----
// octet o: cl=o&15, q=(o>>4)&3, ks=(o>>6)&15, ct=o>>10
// wsb[o*8..+8] = protos[(ct*16+cl)*512 + ks*32 + q*8 ..+8]  (bf16)
__global__ __launch_bounds__(256)
void proto_cvt(const float* __restrict__ protos, __bf16* __restrict__ wsb)
{
    const int o  = blockIdx.x * 256 + threadIdx.x;      // 0..8191
    const int cl = o & 15, q = (o >> 4) & 3, ks = (o >> 6) & 15, ct = o >> 10;
    const int src = (ct * 16 + cl) * D_DIM + ks * 32 + q * 8;
    const f32x4 v0 = *(const f32x4*)(protos + src);
    const f32x4 v1 = *(const f32x4*)(protos + src + 4);
    bf16x8v b;
    b[0]=(__bf16)v0[0]; b[1]=(__bf16)v0[1]; b[2]=(__bf16)v0[2]; b[3]=(__bf16)v0[3];
    b[4]=(__bf16)v1[0]; b[5]=(__bf16)v1[1]; b[6]=(__bf16)v1[2]; b[7]=(__bf16)v1[3];
    *(bf16x8v*)(wsb + o * 8) = b;
}

// ---- main: 256 blocks x 16 waves, barrier-free K-loop ----
// sB holds protos ct=0..6 (112 KB); ct=7 streams from wsb (contiguous, L2-hot).
// A goes global->regs (4x256B contiguous segs/instr) -> sA (wave-private) -> frags.
__global__ __launch_bounds__(THREADS)
void mrc_fused(const float* __restrict__ bfeat,
               const __bf16* __restrict__ wsb,
               const int*   __restrict__ labels,
               const float* __restrict__ weights,
               float*       __restrict__ out,
               int nrows)
{
    __shared__ __bf16 sB[7 * 1024 * 8];          // 114688 B
    __shared__ __bf16 sA[16 * 16 * LDA_ROW];     // 34816 B
    __shared__ float  sScale[16 * 16];           // 1024 B
    __shared__ float  sRed[16];

    const int t = threadIdx.x;
    const int lane = t & 63;
    const int wave = t >> 6;
    const int q = lane >> 4, cl = lane & 15;

    const long long r0 = (long long)blockIdx.x * RPB + wave * 16;

    // labels packed to bits (issued early, complete under the GEMM stream)
    unsigned labbits = 0;
    {
        const int* lb = labels + (r0 + q * 4) * (long long)P_DIM + cl;
#pragma unroll
        for (int reg = 0; reg < 4; ++reg)
#pragma unroll
            for (int ct = 0; ct < 8; ++ct)
                labbits |= (unsigned)(lb[reg * P_DIM + ct * 16] & 1) << (reg * 8 + ct);
    }

    // stage sB (ct 0..6) from ws: lane-contiguous 16 B copies
#pragma unroll
    for (int i = 0; i < 7; ++i) {
        const int o = i * THREADS + t;           // 0..7167
        *(bf16x8v*)&sB[o * 8] = *(const bf16x8v*)(wsb + o * 8);
    }
    __syncthreads();   // only block barrier before the final reduction

    float wcol[8];
#pragma unroll
    for (int ct = 0; ct < 8; ++ct) wcol[ct] = weights[ct * 16 + cl];

    f32x4 acc[8];
#pragma unroll
    for (int ct = 0; ct < 8; ++ct) acc[ct] = (f32x4){0.f, 0.f, 0.f, 0.f};

    // A: super-step ss covers k in [ss*64, ss*64+64); instr j reads row 4j+q,
    // floats cl*4..+4 -> wave instr = 4 rows x 256 B contiguous segments.
    const float* abase = bfeat + (r0 + q) * (long long)D_DIM + cl * 4;
    __bf16* sAw = sA + wave * (16 * LDA_ROW);
    const __bf16* w7 = wsb + 7168 * 8;           // ct=7 block: (ks*64+lane)*8

    f32x4   pf[2][4];   // distance-2 super-step prefetch (A)
    bf16x8v c7[2][2];   // distance-2 super-step prefetch (ct7 fragments)
#pragma unroll
    for (int s = 0; s < 2; ++s)
#pragma unroll
        for (int j = 0; j < 4; ++j)
            pf[s][j] = *(const f32x4*)(abase + j * 4 * D_DIM + s * 64);
#pragma unroll
    for (int s = 0; s < 2; ++s)
#pragma unroll
        for (int k = 0; k < 2; ++k)
            c7[s][k] = *(const bf16x8v*)(w7 + ((s * 2 + k) * 64 + lane) * 8);

    float ssq[4] = {0.f, 0.f, 0.f, 0.f};   // row 4j+q partial sum-of-squares

#pragma unroll
    for (int ss = 0; ss < 8; ++ss) {
        // stage current super-step into wave-private sA (bf16)
#pragma unroll
        for (int j = 0; j < 4; ++j) {
            const f32x4 v = pf[ss & 1][j];
            ssq[j] += v[0]*v[0] + v[1]*v[1] + v[2]*v[2] + v[3]*v[3];
            bf16x4v b;
            b[0]=(__bf16)v[0]; b[1]=(__bf16)v[1]; b[2]=(__bf16)v[2]; b[3]=(__bf16)v[3];
            *(bf16x4v*)&sAw[(4 * j + q) * LDA_ROW + cl * 4] = b;
        }
        if (ss < 6) {
#pragma unroll
            for (int j = 0; j < 4; ++j)
                pf[ss & 1][j] = *(const f32x4*)(abase + j * 4 * D_DIM + (ss + 2) * 64);
        }
#pragma unroll
        for (int kl = 0; kl < 2; ++kl) {
            const int ks = ss * 2 + kl;
            const bf16x8v af = *(const bf16x8v*)&sAw[cl * LDA_ROW + kl * 32 + q * 8];
            const int base = (ks << 6) + (q << 4) + cl;
#pragma unroll
            for (int ct = 0; ct < 7; ++ct) {
                const bf16x8v bfr = *(const bf16x8v*)&sB[(base + (ct << 10)) * 8];
                acc[ct] = __builtin_amdgcn_mfma_f32_16x16x32_bf16(af, bfr, acc[ct], 0, 0, 0);
            }
            acc[7] = __builtin_amdgcn_mfma_f32_16x16x32_bf16(af, c7[ss & 1][kl], acc[7], 0, 0, 0);
        }
        if (ss < 6) {
#pragma unroll
            for (int k = 0; k < 2; ++k)
                c7[ss & 1][k] = *(const bf16x8v*)(w7 + (((ss + 2) * 2 + k) * 64 + lane) * 8);
        }
    }

    // row norms: ssq[j] = partial of row 4j+q, spread over the 16 lanes of group q
#pragma unroll
    for (int j = 0; j < 4; ++j) {
        float s = ssq[j];
        s += __shfl_xor(s, 1, 16);
        s += __shfl_xor(s, 2, 16);
        s += __shfl_xor(s, 4, 16);
        s += __shfl_xor(s, 8, 16);
        if (cl == 0)
            sScale[wave * 16 + 4 * j + q] = 1.0f / (fmaxf(sqrtf(s), 1e-12f) * TEMP);
    }

    // epilogue: masked log-softmax. C/D: col = ct*16+cl, row = q*4+reg
    float pos_acc = 0.f;
#pragma unroll
    for (int reg = 0; reg < 4; ++reg) {
        const float rscale = sScale[wave * 16 + q * 4 + reg];   // LDS broadcast
        float lg[8];
        float m = -3.4e38f;
#pragma unroll
        for (int ct = 0; ct < 8; ++ct) {
            lg[ct] = acc[ct][reg] * rscale;
            m = fmaxf(m, lg[ct]);
        }
        m = fmaxf(m, __shfl_xor(m, 1, 16));
        m = fmaxf(m, __shfl_xor(m, 2, 16));
        m = fmaxf(m, __shfl_xor(m, 4, 16));
        m = fmaxf(m, __shfl_xor(m, 8, 16));

        float s = 0.f, pz = 0.f, msum = 0.f;
#pragma unroll
        for (int ct = 0; ct < 8; ++ct) {
            const float mask = ((labbits >> (reg * 8 + ct)) & 1u) ? wcol[ct] : 0.f;
            const float z = lg[ct] - m;
            s    += __expf(z) * (1.0f - mask);
            pz   += mask * z;
            msum += mask;
        }
        s += __shfl_xor(s, 1, 16);
        s += __shfl_xor(s, 2, 16);
        s += __shfl_xor(s, 4, 16);
        s += __shfl_xor(s, 8, 16);
        pos_acc += pz - logf(s) * msum;   // sum(mask*z) - log(S)*sum(mask)
    }

    // block reduction -> one atomicAdd
    pos_acc += __shfl_xor(pos_acc, 1);
    pos_acc += __shfl_xor(pos_acc, 2);
    pos_acc += __shfl_xor(pos_acc, 4);
    pos_acc += __shfl_xor(pos_acc, 8);
    pos_acc += __shfl_xor(pos_acc, 16);
    pos_acc += __shfl_xor(pos_acc, 32);
    if (lane == 0) sRed[wave] = pos_acc;
    __syncthreads();
    if (t == 0) {
        float total = 0.f;
#pragma unroll
        for (int w = 0; w < 16; ++w) total += sRed[w];
        atomicAdd(out, total * (-TEMP / (float)nrows));   // LAMBDA=1, BT=1
    }
}

extern "C" void kernel_launch(void* const* d_in, const int* in_sizes, int n_in,
                              void* d_out, int out_size, void* d_ws, size_t ws_size,
                              hipStream_t stream) {
    const float* bfeat   = (const float*)d_in[2];
    const float* protos  = (const float*)d_in[3];
    const int*   labels  = (const int*)d_in[4];
    const float* weights = (const float*)d_in[5];
    float* out = (float*)d_out;
    __bf16* wsb = (__bf16*)d_ws;                 // needs 131072 B

    const int nrows = in_sizes[2] / D_DIM;       // 65536

    hipMemsetAsync(d_out, 0, sizeof(float) * out_size, stream);
    proto_cvt<<<32, 256, 0, stream>>>(protos, wsb);
    mrc_fused<<<nrows / RPB, THREADS, 0, stream>>>(bfeat, wsb, labels, weights, out, nrows);
}

// Round 7
// 279.360 us; speedup vs baseline: 1.0463x; 1.0463x over previous
//
#include <hip/hip_runtime.h>
#include <hip/hip_bf16.h>
#include <math.h>

typedef __bf16 bf16x8v __attribute__((ext_vector_type(8)));
typedef __bf16 bf16x4v __attribute__((ext_vector_type(4)));
typedef float  f32x4   __attribute__((ext_vector_type(4)));

#define D_DIM 512
#define P_DIM 128
#define TEMP  0.1f
#define RPB   256
#define THREADS 1024

// ============================================================================
// Kernel 1: protos fp32 -> bf16 fragment order (as R6, verified)
// octet o: cl=o&15, q=(o>>4)&3, ks=(o>>6)&15, ct=o>>10
__global__ __launch_bounds__(256)
void proto_cvt(const float* __restrict__ protos, __bf16* __restrict__ wsP)
{
    const int o  = blockIdx.x * 256 + threadIdx.x;      // 0..8191
    const int cl = o & 15, q = (o >> 4) & 3, ks = (o >> 6) & 15, ct = o >> 10;
    const int src = (ct * 16 + cl) * D_DIM + ks * 32 + q * 8;
    const f32x4 v0 = *(const f32x4*)(protos + src);
    const f32x4 v1 = *(const f32x4*)(protos + src + 4);
    bf16x8v b;
    b[0]=(__bf16)v0[0]; b[1]=(__bf16)v0[1]; b[2]=(__bf16)v0[2]; b[3]=(__bf16)v0[3];
    b[4]=(__bf16)v1[0]; b[5]=(__bf16)v1[1]; b[6]=(__bf16)v1[2]; b[7]=(__bf16)v1[3];
    *(bf16x8v*)(wsP + o * 8) = b;
}

// ============================================================================
// Kernel 2: A fp32 -> bf16 FRAGMENT-ORDER image + per-row scale = 1/(||x||*T).
// One block = one 16-row group. Reads 4x256B segments/instr; writes contiguous.
__global__ __launch_bounds__(256)
void prep_a(const float* __restrict__ bfeat, __bf16* __restrict__ wsA,
            float* __restrict__ scaleOut)
{
    __shared__ __bf16 sT[16 * 528];   // row stride 528 bf16 (1056 B) -> 2-way banks
    const int t = threadIdx.x;
    const long long g = blockIdx.x;                  // row group
    const float* src = bfeat + g * 16 * D_DIM;
    const int row = t >> 4, c0 = t & 15;

    float ssq = 0.f;
#pragma unroll
    for (int i = 0; i < 8; ++i) {
        const int c4 = c0 + 16 * i;                  // float4 column
        const f32x4 v = *(const f32x4*)(src + row * D_DIM + c4 * 4);
        ssq += v[0]*v[0] + v[1]*v[1] + v[2]*v[2] + v[3]*v[3];
        bf16x4v b;
        b[0]=(__bf16)v[0]; b[1]=(__bf16)v[1]; b[2]=(__bf16)v[2]; b[3]=(__bf16)v[3];
        *(bf16x4v*)&sT[row * 528 + c4 * 4] = b;
    }
    ssq += __shfl_xor(ssq, 1, 16);
    ssq += __shfl_xor(ssq, 2, 16);
    ssq += __shfl_xor(ssq, 4, 16);
    ssq += __shfl_xor(ssq, 8, 16);
    if (c0 == 0)
        scaleOut[g * 16 + row] = 1.0f / (fmaxf(sqrtf(ssq), 1e-12f) * TEMP);
    __syncthreads();

    // write fragment order: octet o -> (cl=o&15, q=(o>>4)&3, ks=o>>6)
    __bf16* dst = wsA + g * 8192;
#pragma unroll
    for (int i = 0; i < 4; ++i) {
        const int o  = i * 256 + t;                  // 0..1023
        const int cl = o & 15, q = (o >> 4) & 3, ks = o >> 6;
        *(bf16x8v*)(dst + o * 8) = *(const bf16x8v*)&sT[cl * 528 + ks * 32 + q * 8];
    }
}

// ============================================================================
// Kernel 3: labels -> per-(group,lane) 32-bit mask image (32 MB -> 1 MB).
// lane(cl,q) of group g: bit(reg*8+ct) = labels[g*16 + q*4+reg][ct*16+cl] & 1
__global__ __launch_bounds__(256)
void pack_labels(const int* __restrict__ labels, unsigned* __restrict__ labImg)
{
    const int gid = blockIdx.x * 256 + threadIdx.x;
    const int g = gid >> 6, l = gid & 63;
    const int cl = l & 15, q = l >> 4;
    const int* base = labels + (long long)g * 16 * P_DIM + q * 4 * P_DIM + cl;
    unsigned v = 0;
#pragma unroll
    for (int reg = 0; reg < 4; ++reg)
#pragma unroll
        for (int ct = 0; ct < 8; ++ct)
            v |= (unsigned)(base[reg * P_DIM + ct * 16] & 1) << (reg * 8 + ct);
    labImg[gid] = v;
}

// ============================================================================
// Kernel 4: main GEMM + masked log-softmax. All loads lane-contiguous 16B/4B.
// 256 blocks x 16 waves, protos persistent in LDS, barrier-free K-loop.
__global__ __launch_bounds__(THREADS) __attribute__((amdgpu_waves_per_eu(4, 4)))
void mrc_v2(const __bf16* __restrict__ wsA,
            const __bf16* __restrict__ wsP,
            const unsigned* __restrict__ labImg,
            const float* __restrict__ scaleIn,
            const float* __restrict__ weights,
            float* __restrict__ out, int nrows)
{
    __shared__ __bf16 sB[8 * 1024 * 8];   // 131072 B, fragment order
    __shared__ float  sRed[16];

    const int t = threadIdx.x;
    const int lane = t & 63;
    const int wave = t >> 6;
    const int q = lane >> 4, cl = lane & 15;
    const int g = blockIdx.x * 16 + wave;            // row group of this wave

    // trivial contiguous per-lane loads (complete under sB staging)
    const unsigned labbits = labImg[g * 64 + lane];
    const float sc = scaleIn[g * 16 + cl];           // scale for row cl
    float wcol[8];
#pragma unroll
    for (int ct = 0; ct < 8; ++ct) wcol[ct] = weights[ct * 16 + cl];

    // stage all 8 ct-blocks of protos: lane-contiguous 16 B copies
#pragma unroll
    for (int i = 0; i < 8; ++i) {
        const int o = i * THREADS + t;               // 0..8191
        *(bf16x8v*)&sB[o * 8] = *(const bf16x8v*)(wsP + o * 8);
    }
    __syncthreads();   // only block barrier before the final reduction

    f32x4 acc[8];
#pragma unroll
    for (int ct = 0; ct < 8; ++ct) acc[ct] = (f32x4){0.f, 0.f, 0.f, 0.f};

    // A image: group g octet o = ks*64 + lane -> 1 KB contiguous per wave-instr
    const __bf16* aimg = wsA + (long long)g * 8192;
    bf16x8v pf[4];                                   // distance-4 prefetch
#pragma unroll
    for (int i = 0; i < 4; ++i)
        pf[i] = *(const bf16x8v*)(aimg + (i * 64 + lane) * 8);

#pragma unroll
    for (int ks = 0; ks < 16; ++ks) {
        const bf16x8v af = pf[ks & 3];
        if (ks < 12)
            pf[ks & 3] = *(const bf16x8v*)(aimg + ((ks + 4) * 64 + lane) * 8);
        const int base = (ks << 6) + (q << 4) + cl;
#pragma unroll
        for (int ct = 0; ct < 8; ++ct) {
            const bf16x8v bfr = *(const bf16x8v*)&sB[(base + (ct << 10)) * 8];
            acc[ct] = __builtin_amdgcn_mfma_f32_16x16x32_bf16(af, bfr, acc[ct], 0, 0, 0);
        }
    }

    // epilogue: masked log-softmax. C/D: col = ct*16+cl, row = q*4+reg
    float pos_acc = 0.f;
#pragma unroll
    for (int reg = 0; reg < 4; ++reg) {
        const float rscale = __shfl(sc, q * 4 + reg, 16);  // lane cl==row holds it
        float lg[8];
        float m = -3.4e38f;
#pragma unroll
        for (int ct = 0; ct < 8; ++ct) {
            lg[ct] = acc[ct][reg] * rscale;
            m = fmaxf(m, lg[ct]);
        }
        m = fmaxf(m, __shfl_xor(m, 1, 16));
        m = fmaxf(m, __shfl_xor(m, 2, 16));
        m = fmaxf(m, __shfl_xor(m, 4, 16));
        m = fmaxf(m, __shfl_xor(m, 8, 16));

        float s = 0.f, pz = 0.f, msum = 0.f;
#pragma unroll
        for (int ct = 0; ct < 8; ++ct) {
            const float mask = ((labbits >> (reg * 8 + ct)) & 1u) ? wcol[ct] : 0.f;
            const float z = lg[ct] - m;
            s    += __expf(z) * (1.0f - mask);
            pz   += mask * z;
            msum += mask;
        }
        s += __shfl_xor(s, 1, 16);
        s += __shfl_xor(s, 2, 16);
        s += __shfl_xor(s, 4, 16);
        s += __shfl_xor(s, 8, 16);
        pos_acc += pz - logf(s) * msum;   // sum(mask*z) - log(S)*sum(mask)
    }

    pos_acc += __shfl_xor(pos_acc, 1);
    pos_acc += __shfl_xor(pos_acc, 2);
    pos_acc += __shfl_xor(pos_acc, 4);
    pos_acc += __shfl_xor(pos_acc, 8);
    pos_acc += __shfl_xor(pos_acc, 16);
    pos_acc += __shfl_xor(pos_acc, 32);
    if (lane == 0) sRed[wave] = pos_acc;
    __syncthreads();
    if (t == 0) {
        float total = 0.f;
#pragma unroll
        for (int w = 0; w < 16; ++w) total += sRed[w];
        atomicAdd(out, total * (-TEMP / (float)nrows));   // LAMBDA=1, BT=1
    }
}

// ============================================================================
// Fallback (ws too small): R5 kernel verbatim — self-contained, no workspace.
__global__ __launch_bounds__(THREADS)
void mrc_fused_fb(const float* __restrict__ bfeat,
                  const float* __restrict__ protos,
                  const int*   __restrict__ labels,
                  const float* __restrict__ weights,
                  float*       __restrict__ out,
                  int nrows)
{
    __shared__ __bf16 sB[P_DIM * D_DIM];
    __shared__ float  sRed[16];
    const int t = threadIdx.x;
    const int lane = t & 63;
    const int wave = t >> 6;
    const int q = lane >> 4, cl = lane & 15;
    const long long r0 = (long long)blockIdx.x * RPB + wave * 16;
    unsigned int labbits = 0;
    {
        const int* lb = labels + r0 * (long long)P_DIM + q * 4 * P_DIM + cl;
#pragma unroll
        for (int reg = 0; reg < 4; ++reg)
#pragma unroll
            for (int ct = 0; ct < 8; ++ct)
                labbits |= (unsigned)(lb[reg * P_DIM + ct * 16] & 1) << (reg * 8 + ct);
    }
#pragma unroll
    for (int i = 0; i < 8; ++i) {
        const int o = i * THREADS + t;
        const int p = ((o >> 10) << 4) | (o & 15);
        const int k = (((o >> 6) & 15) << 5) | (((o >> 4) & 3) << 3);
        const f32x4 v0 = *(const f32x4*)(protos + p * D_DIM + k);
        const f32x4 v1 = *(const f32x4*)(protos + p * D_DIM + k + 4);
        bf16x8v b;
        b[0]=(__bf16)v0[0]; b[1]=(__bf16)v0[1]; b[2]=(__bf16)v0[2]; b[3]=(__bf16)v0[3];
        b[4]=(__bf16)v1[0]; b[5]=(__bf16)v1[1]; b[6]=(__bf16)v1[2]; b[7]=(__bf16)v1[3];
        *(bf16x8v*)&sB[o * 8] = b;
    }
    __syncthreads();
    const float* arow = bfeat + (r0 + cl) * (long long)D_DIM + q * 8;
    float wcol[8];
#pragma unroll
    for (int ct = 0; ct < 8; ++ct) wcol[ct] = weights[ct * 16 + cl];
    f32x4 acc[8];
#pragma unroll
    for (int ct = 0; ct < 8; ++ct) acc[ct] = (f32x4){0.f, 0.f, 0.f, 0.f};
    float ss = 0.f;
    f32x4 p[4][2];
#pragma unroll
    for (int i = 0; i < 4; ++i) {
        p[i][0] = *(const f32x4*)(arow + i * 32);
        p[i][1] = *(const f32x4*)(arow + i * 32 + 4);
    }
#pragma unroll
    for (int ks = 0; ks < 16; ++ks) {
        const f32x4 c0 = p[ks & 3][0], c1 = p[ks & 3][1];
        if (ks < 12) {
            p[ks & 3][0] = *(const f32x4*)(arow + (ks + 4) * 32);
            p[ks & 3][1] = *(const f32x4*)(arow + (ks + 4) * 32 + 4);
        }
        ss += c0[0]*c0[0] + c0[1]*c0[1] + c0[2]*c0[2] + c0[3]*c0[3]
            + c1[0]*c1[0] + c1[1]*c1[1] + c1[2]*c1[2] + c1[3]*c1[3];
        bf16x8v af;
        af[0]=(__bf16)c0[0]; af[1]=(__bf16)c0[1]; af[2]=(__bf16)c0[2]; af[3]=(__bf16)c0[3];
        af[4]=(__bf16)c1[0]; af[5]=(__bf16)c1[1]; af[6]=(__bf16)c1[2]; af[7]=(__bf16)c1[3];
        const int base = (ks << 6) + (q << 4) + cl;
#pragma unroll
        for (int ct = 0; ct < 8; ++ct) {
            const bf16x8v bfr = *(const bf16x8v*)&sB[(base + (ct << 10)) * 8];
            acc[ct] = __builtin_amdgcn_mfma_f32_16x16x32_bf16(af, bfr, acc[ct], 0, 0, 0);
        }
    }
    ss += __shfl_xor(ss, 16);
    ss += __shfl_xor(ss, 32);
    const float scale = 1.0f / (fmaxf(sqrtf(ss), 1e-12f) * TEMP);
    float pos_acc = 0.f;
#pragma unroll
    for (int reg = 0; reg < 4; ++reg) {
        const float rscale = __shfl(scale, q * 4 + reg, 16);
        float lg[8];
        float m = -3.4e38f;
#pragma unroll
        for (int ct = 0; ct < 8; ++ct) {
            lg[ct] = acc[ct][reg] * rscale;
            m = fmaxf(m, lg[ct]);
        }
        m = fmaxf(m, __shfl_xor(m, 1, 16));
        m = fmaxf(m, __shfl_xor(m, 2, 16));
        m = fmaxf(m, __shfl_xor(m, 4, 16));
        m = fmaxf(m, __shfl_xor(m, 8, 16));
        float s = 0.f, pz = 0.f, msum = 0.f;
#pragma unroll
        for (int ct = 0; ct < 8; ++ct) {
            const float mask = ((labbits >> (reg * 8 + ct)) & 1u) ? wcol[ct] : 0.f;
            const float z = lg[ct] - m;
            s    += __expf(z) * (1.0f - mask);
            pz   += mask * z;
            msum += mask;
        }
        s += __shfl_xor(s, 1, 16);
        s += __shfl_xor(s, 2, 16);
        s += __shfl_xor(s, 4, 16);
        s += __shfl_xor(s, 8, 16);
        pos_acc += pz - logf(s) * msum;
    }
    pos_acc += __shfl_xor(pos_acc, 1);
    pos_acc += __shfl_xor(pos_acc, 2);
    pos_acc += __shfl_xor(pos_acc, 4);
    pos_acc += __shfl_xor(pos_acc, 8);
    pos_acc += __shfl_xor(pos_acc, 16);
    pos_acc += __shfl_xor(pos_acc, 32);
    if (lane == 0) sRed[wave] = pos_acc;
    __syncthreads();
    if (t == 0) {
        float total = 0.f;
#pragma unroll
        for (int w = 0; w < 16; ++w) total += sRed[w];
        atomicAdd(out, total * (-TEMP / (float)nrows));
    }
}

extern "C" void kernel_launch(void* const* d_in, const int* in_sizes, int n_in,
                              void* d_out, int out_size, void* d_ws, size_t ws_size,
                              hipStream_t stream) {
    const float* bfeat   = (const float*)d_in[2];
    const float* protos  = (const float*)d_in[3];
    const int*   labels  = (const int*)d_in[4];
    const float* weights = (const float*)d_in[5];
    float* out = (float*)d_out;

    const int nrows  = in_sizes[2] / D_DIM;          // 65536
    const int groups = nrows / 16;                   // 4096

    // ws layout: A-image | proto-image | scale | labbits
    const size_t offA = 0;
    const size_t offP = offA + (size_t)nrows * D_DIM * sizeof(__bf16);  // 64 MB
    const size_t offS = offP + 131072;
    const size_t offL = offS + (size_t)nrows * sizeof(float);
    const size_t need = offL + (size_t)groups * 64 * sizeof(unsigned);

    hipMemsetAsync(d_out, 0, sizeof(float) * out_size, stream);

    if (ws_size >= need) {
        __bf16*   wsA = (__bf16*)((char*)d_ws + offA);
        __bf16*   wsP = (__bf16*)((char*)d_ws + offP);
        float*    wsS = (float*)((char*)d_ws + offS);
        unsigned* wsL = (unsigned*)((char*)d_ws + offL);
        proto_cvt<<<32, 256, 0, stream>>>(protos, wsP);
        prep_a<<<groups, 256, 0, stream>>>(bfeat, wsA, wsS);
        pack_labels<<<groups / 4, 256, 0, stream>>>(labels, wsL);
        mrc_v2<<<nrows / RPB, THREADS, 0, stream>>>(wsA, wsP, wsL, wsS, weights, out, nrows);
    } else {
        mrc_fused_fb<<<nrows / RPB, THREADS, 0, stream>>>(bfeat, protos, labels, weights, out, nrows);
    }
}

// Round 8
// 277.183 us; speedup vs baseline: 1.0545x; 1.0079x over previous
//
#include <hip/hip_runtime.h>
#include <hip/hip_bf16.h>
#include <math.h>

typedef __bf16 bf16x8v __attribute__((ext_vector_type(8)));
typedef __bf16 bf16x4v __attribute__((ext_vector_type(4)));
typedef float  f32x4   __attribute__((ext_vector_type(4)));

#define D_DIM 512
#define P_DIM 128
#define TEMP  0.1f
#define RPB   256
#define THREADS 1024

// ============================================================================
// Kernel 1 (merged prep): blocks [0,4096) = per-group A-image + scale + label
// pack; blocks [4096,4128) = proto fp32 -> bf16 fragment image.
// Group block g: reads A rows g*16.. (32 KB contiguous) + labels (8 KB contig).
__global__ __launch_bounds__(256)
void prep(const float* __restrict__ bfeat,
          const float* __restrict__ protos,
          const int*   __restrict__ labels,
          __bf16* __restrict__ wsA, __bf16* __restrict__ wsP,
          float* __restrict__ scaleOut, unsigned* __restrict__ labImg)
{
    const int t = threadIdx.x;
    if (blockIdx.x >= 4096) {
        // ---- proto_cvt: octet o -> cl=o&15, q=(o>>4)&3, ks=(o>>6)&15, ct=o>>10
        const int o  = (blockIdx.x - 4096) * 256 + t;    // 0..8191
        const int cl = o & 15, q = (o >> 4) & 3, ks = (o >> 6) & 15, ct = o >> 10;
        const int src = (ct * 16 + cl) * D_DIM + ks * 32 + q * 8;
        const f32x4 v0 = *(const f32x4*)(protos + src);
        const f32x4 v1 = *(const f32x4*)(protos + src + 4);
        bf16x8v b;
        b[0]=(__bf16)v0[0]; b[1]=(__bf16)v0[1]; b[2]=(__bf16)v0[2]; b[3]=(__bf16)v0[3];
        b[4]=(__bf16)v1[0]; b[5]=(__bf16)v1[1]; b[6]=(__bf16)v1[2]; b[7]=(__bf16)v1[3];
        *(bf16x8v*)(wsP + o * 8) = b;
        return;
    }

    __shared__ __bf16 sT[16 * 528];   // row stride 528 bf16 -> 2-way banks only
    const long long g = blockIdx.x;                  // row group
    const float* src = bfeat + g * 16 * D_DIM;
    const int row = t >> 4, c0 = t & 15;

    // ---- label pack (threads 0..63): group-local 8 KB region, issued first ----
    unsigned lv = 0;
    if (t < 64) {
        const int cl = t & 15, q = t >> 4;
        const int* base = labels + g * 16 * P_DIM + q * 4 * P_DIM + cl;
#pragma unroll
        for (int reg = 0; reg < 4; ++reg)
#pragma unroll
            for (int ct = 0; ct < 8; ++ct)
                lv |= (unsigned)(base[reg * P_DIM + ct * 16] & 1) << (reg * 8 + ct);
    }

    // ---- A: fp32 read (4 rows x 256 B contiguous per instr), ssq, bf16 to LDS
    float ssq = 0.f;
#pragma unroll
    for (int i = 0; i < 8; ++i) {
        const int c4 = c0 + 16 * i;                  // float4 column
        const f32x4 v = *(const f32x4*)(src + row * D_DIM + c4 * 4);
        ssq += v[0]*v[0] + v[1]*v[1] + v[2]*v[2] + v[3]*v[3];
        bf16x4v b;
        b[0]=(__bf16)v[0]; b[1]=(__bf16)v[1]; b[2]=(__bf16)v[2]; b[3]=(__bf16)v[3];
        *(bf16x4v*)&sT[row * 528 + c4 * 4] = b;
    }
    ssq += __shfl_xor(ssq, 1, 16);
    ssq += __shfl_xor(ssq, 2, 16);
    ssq += __shfl_xor(ssq, 4, 16);
    ssq += __shfl_xor(ssq, 8, 16);
    if (c0 == 0)
        scaleOut[g * 16 + row] = 1.0f / (fmaxf(sqrtf(ssq), 1e-12f) * TEMP);
    if (t < 64) labImg[g * 64 + t] = lv;
    __syncthreads();

    // ---- write A fragment image: octet o -> (cl=o&15, q=(o>>4)&3, ks=o>>6)
    __bf16* dst = wsA + g * 8192;
#pragma unroll
    for (int i = 0; i < 4; ++i) {
        const int o  = i * 256 + t;                  // 0..1023
        const int cl = o & 15, q = (o >> 4) & 3, ks = o >> 6;
        *(bf16x8v*)(dst + o * 8) = *(const bf16x8v*)&sT[cl * 528 + ks * 32 + q * 8];
    }
}

// ============================================================================
// Kernel 2: main GEMM + masked log-softmax (R7-proven). All loads contiguous.
__global__ __launch_bounds__(THREADS) __attribute__((amdgpu_waves_per_eu(4, 4)))
void mrc_v2(const __bf16* __restrict__ wsA,
            const __bf16* __restrict__ wsP,
            const unsigned* __restrict__ labImg,
            const float* __restrict__ scaleIn,
            const float* __restrict__ weights,
            float* __restrict__ out, int nrows)
{
    __shared__ __bf16 sB[8 * 1024 * 8];   // 131072 B, fragment order
    __shared__ float  sRed[16];

    const int t = threadIdx.x;
    const int lane = t & 63;
    const int wave = t >> 6;
    const int q = lane >> 4, cl = lane & 15;
    const int g = blockIdx.x * 16 + wave;            // row group of this wave

    const unsigned labbits = labImg[g * 64 + lane];
    const float sc = scaleIn[g * 16 + cl];           // scale for row cl
    float wcol[8];
#pragma unroll
    for (int ct = 0; ct < 8; ++ct) wcol[ct] = weights[ct * 16 + cl];

#pragma unroll
    for (int i = 0; i < 8; ++i) {
        const int o = i * THREADS + t;               // 0..8191
        *(bf16x8v*)&sB[o * 8] = *(const bf16x8v*)(wsP + o * 8);
    }
    __syncthreads();   // only block barrier before the final reduction

    f32x4 acc[8];
#pragma unroll
    for (int ct = 0; ct < 8; ++ct) acc[ct] = (f32x4){0.f, 0.f, 0.f, 0.f};

    // A image: octet o = ks*64 + lane -> 1 KB contiguous per wave-instr
    const __bf16* aimg = wsA + (long long)g * 8192;
    bf16x8v pf[4];                                   // distance-4 prefetch
#pragma unroll
    for (int i = 0; i < 4; ++i)
        pf[i] = *(const bf16x8v*)(aimg + (i * 64 + lane) * 8);

#pragma unroll
    for (int ks = 0; ks < 16; ++ks) {
        const bf16x8v af = pf[ks & 3];
        if (ks < 12)
            pf[ks & 3] = *(const bf16x8v*)(aimg + ((ks + 4) * 64 + lane) * 8);
        const int base = (ks << 6) + (q << 4) + cl;
#pragma unroll
        for (int ct = 0; ct < 8; ++ct) {
            const bf16x8v bfr = *(const bf16x8v*)&sB[(base + (ct << 10)) * 8];
            acc[ct] = __builtin_amdgcn_mfma_f32_16x16x32_bf16(af, bfr, acc[ct], 0, 0, 0);
        }
    }

    // epilogue: masked log-softmax. C/D: col = ct*16+cl, row = q*4+reg
    float pos_acc = 0.f;
#pragma unroll
    for (int reg = 0; reg < 4; ++reg) {
        const float rscale = __shfl(sc, q * 4 + reg, 16);  // lane cl==row holds it
        float lg[8];
        float m = -3.4e38f;
#pragma unroll
        for (int ct = 0; ct < 8; ++ct) {
            lg[ct] = acc[ct][reg] * rscale;
            m = fmaxf(m, lg[ct]);
        }
        m = fmaxf(m, __shfl_xor(m, 1, 16));
        m = fmaxf(m, __shfl_xor(m, 2, 16));
        m = fmaxf(m, __shfl_xor(m, 4, 16));
        m = fmaxf(m, __shfl_xor(m, 8, 16));

        float s = 0.f, pz = 0.f, msum = 0.f;
#pragma unroll
        for (int ct = 0; ct < 8; ++ct) {
            const float mask = ((labbits >> (reg * 8 + ct)) & 1u) ? wcol[ct] : 0.f;
            const float z = lg[ct] - m;
            s    += __expf(z) * (1.0f - mask);
            pz   += mask * z;
            msum += mask;
        }
        s += __shfl_xor(s, 1, 16);
        s += __shfl_xor(s, 2, 16);
        s += __shfl_xor(s, 4, 16);
        s += __shfl_xor(s, 8, 16);
        pos_acc += pz - logf(s) * msum;   // sum(mask*z) - log(S)*sum(mask)
    }

    pos_acc += __shfl_xor(pos_acc, 1);
    pos_acc += __shfl_xor(pos_acc, 2);
    pos_acc += __shfl_xor(pos_acc, 4);
    pos_acc += __shfl_xor(pos_acc, 8);
    pos_acc += __shfl_xor(pos_acc, 16);
    pos_acc += __shfl_xor(pos_acc, 32);
    if (lane == 0) sRed[wave] = pos_acc;
    __syncthreads();
    if (t == 0) {
        float total = 0.f;
#pragma unroll
        for (int w = 0; w < 16; ++w) total += sRed[w];
        atomicAdd(out, total * (-TEMP / (float)nrows));   // LAMBDA=1, BT=1
    }
}

// ============================================================================
// Fallback (ws too small): R5 kernel verbatim — self-contained, no workspace.
__global__ __launch_bounds__(THREADS)
void mrc_fused_fb(const float* __restrict__ bfeat,
                  const float* __restrict__ protos,
                  const int*   __restrict__ labels,
                  const float* __restrict__ weights,
                  float*       __restrict__ out,
                  int nrows)
{
    __shared__ __bf16 sB[P_DIM * D_DIM];
    __shared__ float  sRed[16];
    const int t = threadIdx.x;
    const int lane = t & 63;
    const int wave = t >> 6;
    const int q = lane >> 4, cl = lane & 15;
    const long long r0 = (long long)blockIdx.x * RPB + wave * 16;
    unsigned int labbits = 0;
    {
        const int* lb = labels + r0 * (long long)P_DIM + q * 4 * P_DIM + cl;
#pragma unroll
        for (int reg = 0; reg < 4; ++reg)
#pragma unroll
            for (int ct = 0; ct < 8; ++ct)
                labbits |= (unsigned)(lb[reg * P_DIM + ct * 16] & 1) << (reg * 8 + ct);
    }
#pragma unroll
    for (int i = 0; i < 8; ++i) {
        const int o = i * THREADS + t;
        const int p = ((o >> 10) << 4) | (o & 15);
        const int k = (((o >> 6) & 15) << 5) | (((o >> 4) & 3) << 3);
        const f32x4 v0 = *(const f32x4*)(protos + p * D_DIM + k);
        const f32x4 v1 = *(const f32x4*)(protos + p * D_DIM + k + 4);
        bf16x8v b;
        b[0]=(__bf16)v0[0]; b[1]=(__bf16)v0[1]; b[2]=(__bf16)v0[2]; b[3]=(__bf16)v0[3];
        b[4]=(__bf16)v1[0]; b[5]=(__bf16)v1[1]; b[6]=(__bf16)v1[2]; b[7]=(__bf16)v1[3];
        *(bf16x8v*)&sB[o * 8] = b;
    }
    __syncthreads();
    const float* arow = bfeat + (r0 + cl) * (long long)D_DIM + q * 8;
    float wcol[8];
#pragma unroll
    for (int ct = 0; ct < 8; ++ct) wcol[ct] = weights[ct * 16 + cl];
    f32x4 acc[8];
#pragma unroll
    for (int ct = 0; ct < 8; ++ct) acc[ct] = (f32x4){0.f, 0.f, 0.f, 0.f};
    float ss = 0.f;
    f32x4 p[4][2];
#pragma unroll
    for (int i = 0; i < 4; ++i) {
        p[i][0] = *(const f32x4*)(arow + i * 32);
        p[i][1] = *(const f32x4*)(arow + i * 32 + 4);
    }
#pragma unroll
    for (int ks = 0; ks < 16; ++ks) {
        const f32x4 c0 = p[ks & 3][0], c1 = p[ks & 3][1];
        if (ks < 12) {
            p[ks & 3][0] = *(const f32x4*)(arow + (ks + 4) * 32);
            p[ks & 3][1] = *(const f32x4*)(arow + (ks + 4) * 32 + 4);
        }
        ss += c0[0]*c0[0] + c0[1]*c0[1] + c0[2]*c0[2] + c0[3]*c0[3]
            + c1[0]*c1[0] + c1[1]*c1[1] + c1[2]*c1[2] + c1[3]*c1[3];
        bf16x8v af;
        af[0]=(__bf16)c0[0]; af[1]=(__bf16)c0[1]; af[2]=(__bf16)c0[2]; af[3]=(__bf16)c0[3];
        af[4]=(__bf16)c1[0]; af[5]=(__bf16)c1[1]; af[6]=(__bf16)c1[2]; af[7]=(__bf16)c1[3];
        const int base = (ks << 6) + (q << 4) + cl;
#pragma unroll
        for (int ct = 0; ct < 8; ++ct) {
            const bf16x8v bfr = *(const bf16x8v*)&sB[(base + (ct << 10)) * 8];
            acc[ct] = __builtin_amdgcn_mfma_f32_16x16x32_bf16(af, bfr, acc[ct], 0, 0, 0);
        }
    }
    ss += __shfl_xor(ss, 16);
    ss += __shfl_xor(ss, 32);
    const float scale = 1.0f / (fmaxf(sqrtf(ss), 1e-12f) * TEMP);
    float pos_acc = 0.f;
#pragma unroll
    for (int reg = 0; reg < 4; ++reg) {
        const float rscale = __shfl(scale, q * 4 + reg, 16);
        float lg[8];
        float m = -3.4e38f;
#pragma unroll
        for (int ct = 0; ct < 8; ++ct) {
            lg[ct] = acc[ct][reg] * rscale;
            m = fmaxf(m, lg[ct]);
        }
        m = fmaxf(m, __shfl_xor(m, 1, 16));
        m = fmaxf(m, __shfl_xor(m, 2, 16));
        m = fmaxf(m, __shfl_xor(m, 4, 16));
        m = fmaxf(m, __shfl_xor(m, 8, 16));
        float s = 0.f, pz = 0.f, msum = 0.f;
#pragma unroll
        for (int ct = 0; ct < 8; ++ct) {
            const float mask = ((labbits >> (reg * 8 + ct)) & 1u) ? wcol[ct] : 0.f;
            const float z = lg[ct] - m;
            s    += __expf(z) * (1.0f - mask);
            pz   += mask * z;
            msum += mask;
        }
        s += __shfl_xor(s, 1, 16);
        s += __shfl_xor(s, 2, 16);
        s += __shfl_xor(s, 4, 16);
        s += __shfl_xor(s, 8, 16);
        pos_acc += pz - logf(s) * msum;
    }
    pos_acc += __shfl_xor(pos_acc, 1);
    pos_acc += __shfl_xor(pos_acc, 2);
    pos_acc += __shfl_xor(pos_acc, 4);
    pos_acc += __shfl_xor(pos_acc, 8);
    pos_acc += __shfl_xor(pos_acc, 16);
    pos_acc += __shfl_xor(pos_acc, 32);
    if (lane == 0) sRed[wave] = pos_acc;
    __syncthreads();
    if (t == 0) {
        float total = 0.f;
#pragma unroll
        for (int w = 0; w < 16; ++w) total += sRed[w];
        atomicAdd(out, total * (-TEMP / (float)nrows));
    }
}

extern "C" void kernel_launch(void* const* d_in, const int* in_sizes, int n_in,
                              void* d_out, int out_size, void* d_ws, size_t ws_size,
                              hipStream_t stream) {
    const float* bfeat   = (const float*)d_in[2];
    const float* protos  = (const float*)d_in[3];
    const int*   labels  = (const int*)d_in[4];
    const float* weights = (const float*)d_in[5];
    float* out = (float*)d_out;

    const int nrows  = in_sizes[2] / D_DIM;          // 65536
    const int groups = nrows / 16;                   // 4096

    // ws layout: A-image | proto-image | scale | labbits
    const size_t offA = 0;
    const size_t offP = offA + (size_t)nrows * D_DIM * sizeof(__bf16);  // 64 MB
    const size_t offS = offP + 131072;
    const size_t offL = offS + (size_t)nrows * sizeof(float);
    const size_t need = offL + (size_t)groups * 64 * sizeof(unsigned);

    hipMemsetAsync(d_out, 0, sizeof(float) * out_size, stream);

    if (ws_size >= need) {
        __bf16*   wsA = (__bf16*)((char*)d_ws + offA);
        __bf16*   wsP = (__bf16*)((char*)d_ws + offP);
        float*    wsS = (float*)((char*)d_ws + offS);
        unsigned* wsL = (unsigned*)((char*)d_ws + offL);
        prep<<<groups + 32, 256, 0, stream>>>(bfeat, protos, labels, wsA, wsP, wsS, wsL);
        mrc_v2<<<nrows / RPB, THREADS, 0, stream>>>(wsA, wsP, wsL, wsS, weights, out, nrows);
    } else {
        mrc_fused_fb<<<nrows / RPB, THREADS, 0, stream>>>(bfeat, protos, labels, weights, out, nrows);
    }
}